// Round 22
// baseline (51.004 us; speedup 1.0000x reference)
//
#include <hip/hip_runtime.h>

// SITH: out[t,o,f] = subset[o] * sum_n invL_sub[o,n] * ts[t,n,f]
//   ts[t,n,f] = d[n]*ts[t-1,n,f] + decay[n]*inp[t,f]
// invL_sub row o EXACTLY banded: n in [4o, 4o+8]. State unscaled; decay*subset
// folded into taps.
//
// R19 vs R14: streaming store pattern.
//  - pass2 block = (o-group, chunk), 512 thr = 8 waves = 8 f-slices. Per
//    4-step group the 4x5x512 tile is staged in LDS (double-buffered, one
//    barrier) and stored cooperatively: float4 per lane, 1 KB contiguous
//    per instruction, o-rows consecutive -> 10 KB sequential runs. Plain
//    stores (L2 write-back) so the barrier drains to L2, not HBM.
//  - P holds true boundary states again: new pass1b (XCD-pinned in-place
//    d^32 Horner scan) so pass2 init is just 25 loads.

#define NF   512
#define NN   408
#define NO   100
#define NC   16     // time chunks
#define TC   32     // steps per chunk
#define NB   15     // boundary chunks stored (0..14)
#define TAPS 9
#define OPG  5      // outputs per o-group
#define NG   20     // o-groups (NG*OPG == NO)
#define ROWS 25     // state rows per o-group window [20g, 20g+24]
#define NPT  4      // n-rows per pass1a thread

// ---------------- Pass 1a: per-chunk LOCAL sums ----------------
// grid (8, 26, 15): x = f-slice (XCD), y = 16-row band, z = chunk.
__global__ __launch_bounds__(256) void sith_pass1a(
    const float* __restrict__ inp, const float* __restrict__ d,
    float* __restrict__ P)
{
    int fs = blockIdx.x;
    int a  = blockIdx.y;
    int b  = blockIdx.z;
    int tid = threadIdx.x;
    int lane = tid & 63;
    int y = tid >> 6;
    int n0 = a * 16 + y * NPT;
    if (n0 >= NN) return;
    int f = fs * 64 + lane;

    float dreg[NPT], st[NPT];
    #pragma unroll
    for (int q = 0; q < NPT; ++q) {
        dreg[q] = d[n0 + q];
        st[q] = 0.f;
    }
    const float* ip = inp + b * TC * NF + f;
    #pragma unroll
    for (int tt = 0; tt < TC; tt += 8) {
        float x[8];
        #pragma unroll
        for (int u = 0; u < 8; ++u) x[u] = ip[(tt + u) * NF];
        #pragma unroll
        for (int u = 0; u < 8; ++u) {
            #pragma unroll
            for (int q = 0; q < NPT; ++q)
                st[q] = fmaf(dreg[q], st[q], x[u]);
        }
    }
    #pragma unroll
    for (int q = 0; q < NPT; ++q)
        P[b * (NN * NF) + (n0 + q) * NF + f] = st[q];
}

// ---------------- Pass 1b: in-place cross-chunk scan ----------------
// grid (8, 102): x = f-slice (XCD-pinned, L2-local), y -> 4 n-rows.
// S_b = L_b + d^32 * S_{b-1}.
__global__ __launch_bounds__(256) void sith_pass1b(
    const float* __restrict__ d, float* __restrict__ P)
{
    int fs = blockIdx.x;
    int n  = blockIdx.y * 4 + (threadIdx.x >> 6);   // 0..407
    int f  = fs * 64 + (threadIdx.x & 63);
    float dn = d[n];
    float d2 = dn * dn, d4 = d2 * d2, d8 = d4 * d4, d16 = d8 * d8;
    float d32 = d16 * d16;

    float* Pb = P + n * NF + f;
    float v[NB];
    #pragma unroll
    for (int b = 0; b < NB; ++b) v[b] = Pb[b * (NN * NF)];
    float acc = v[0];
    #pragma unroll
    for (int b = 1; b < NB; ++b) {
        acc = fmaf(d32, acc, v[b]);
        Pb[b * (NN * NF)] = acc;
    }
}

// ---------------- Pass 2: scan + projection, streaming stores ----------
// grid (20, 16): x = o-group g, y = chunk c. 512 thr = 8 waves = 8 f-slices.
__global__ __launch_bounds__(512) void sith_pass2(
    const float* __restrict__ inp, const float* __restrict__ invL,
    const float* __restrict__ d, const float* __restrict__ decay,
    const float* __restrict__ subset, const float* __restrict__ P,
    float* __restrict__ out)
{
    __shared__ float lds[2][20][NF];      // 2 x 40 KB

    int g = blockIdx.x;                   // 0..19
    int c = blockIdx.y;                   // 0..15
    int tid = threadIdx.x;
    int lane = tid & 63;
    int w = tid >> 6;                     // 0..7 = f-slice
    int f = w * 64 + lane;
    int nbase = NG * g;

    float dreg[ROWS], p[ROWS];
    #pragma unroll
    for (int j = 0; j < ROWS; ++j) {
        int n = nbase + j;                // <= 404: no guards
        dreg[j] = d[n];
        p[j] = (c == 0) ? 0.f : P[(c - 1) * (NN * NF) + n * NF + f];
    }

    float L[OPG][TAPS];
    #pragma unroll
    for (int k = 0; k < OPG; ++k) {
        int o = OPG * g + k;
        float sub = subset[o];
        #pragma unroll
        for (int dd = 0; dd < TAPS; ++dd) {
            int n = nbase + 4 * k + dd;
            L[k][dd] = invL[o * NN + n] * sub * decay[n];
        }
    }

    const float* ip = inp + f;
    int t0 = c * TC;
    int srow = tid >> 7;                  // 0..3: row offset within store round
    int f4   = (tid & 127) << 2;          // float index within row

#define SITH_STEP(s, xv)                                                   \
    {                                                                      \
        _Pragma("unroll")                                                  \
        for (int j = 0; j < ROWS; ++j)                                     \
            p[j] = fmaf(dreg[j], p[j], (xv));                              \
        _Pragma("unroll")                                                  \
        for (int k = 0; k < OPG; ++k) {                                    \
            float a0 = 0.f;                                                \
            _Pragma("unroll")                                              \
            for (int dd = 0; dd < TAPS; ++dd)                              \
                a0 = fmaf(L[k][dd], p[4 * k + dd], a0);                    \
            acc[s][k] = a0;                                                \
        }                                                                  \
    }

    float xb0 = ip[(t0 + 0) * NF];
    float xb1 = ip[(t0 + 1) * NF];
    float xb2 = ip[(t0 + 2) * NF];
    float xb3 = ip[(t0 + 3) * NF];

    for (int tq = 0; tq < TC; tq += 4) {
        int tp = t0 + tq + 4;
        float xn0 = ip[((tp + 0) & 511) * NF];
        float xn1 = ip[((tp + 1) & 511) * NF];
        float xn2 = ip[((tp + 2) & 511) * NF];
        float xn3 = ip[((tp + 3) & 511) * NF];

        float acc[4][OPG];
        SITH_STEP(0, xb0);
        SITH_STEP(1, xb1);
        SITH_STEP(2, xb2);
        SITH_STEP(3, xb3);

        int buf = (tq >> 2) & 1;
        #pragma unroll
        for (int s = 0; s < 4; ++s)
            #pragma unroll
            for (int k = 0; k < OPG; ++k)
                lds[buf][s * OPG + k][f] = acc[s][k];

        __syncthreads();                  // drains LDS writes + L2-bound stores

        // cooperative streaming store: 5 rounds x (4 rows x 2 KB contiguous)
        #pragma unroll
        for (int r = 0; r < 5; ++r) {
            int row = r * 4 + srow;       // 0..19 = s*5 + k
            int s   = row / OPG;
            int k   = row - s * OPG;
            float4 v = *reinterpret_cast<const float4*>(&lds[buf][row][f4]);
            *reinterpret_cast<float4*>(
                &out[((t0 + tq + s) * NO + OPG * g + k) * NF + f4]) = v;
        }

        xb0 = xn0; xb1 = xn1; xb2 = xn2; xb3 = xn3;
    }
#undef SITH_STEP
}

extern "C" void kernel_launch(void* const* d_in, const int* in_sizes, int n_in,
                              void* d_out, int out_size, void* d_ws, size_t ws_size,
                              hipStream_t stream)
{
    const float* inp    = (const float*)d_in[0];
    const float* invL   = (const float*)d_in[1];
    const float* d      = (const float*)d_in[2];
    const float* decay  = (const float*)d_in[3];
    const float* subset = (const float*)d_in[4];
    float* out = (float*)d_out;
    float* P   = (float*)d_ws;   // 15 * 408 * 512 * 4 B = 12.5 MB

    sith_pass1a<<<dim3(8, 26, NB), 256, 0, stream>>>(inp, d, P);
    sith_pass1b<<<dim3(8, 102), 256, 0, stream>>>(d, P);
    sith_pass2<<<dim3(NG, NC), 512, 0, stream>>>(inp, invL, d, decay, subset, P, out);
}

// Round 23
// 46.390 us; speedup vs baseline: 1.0995x; 1.0995x over previous
//
#include <hip/hip_runtime.h>

// SITH: out[t,o,f] = subset[o] * sum_n invL_sub[o,n] * ts[t,n,f]
//   ts[t,n,f] = d[n]*ts[t-1,n,f] + decay[n]*inp[t,f]
// invL_sub row o EXACTLY banded: n in [4o, 4o+8] (9 taps). State unscaled;
// decay*subset folded into taps.
//
// R23: fill-identical store granularity, barrier-free.
//  - pass2 thread = (o, 4 consecutive f); wave = (o, 256-f half):
//    every store is 64 lanes x float4 = 1024 B CONTIGUOUS (first version
//    to match the fill kernel's per-instruction write shape, no LDS).
//  - OPG=1 -> 9 rows x 4 f per thread (~75 VGPR), 3200 waves = 3.1/SIMD.
//  - P = true boundary states via XCD-pinned pass1b; init = 9 float4 loads.

#define NF   512
#define NN   408
#define NO   100
#define NC   16     // time chunks
#define TC   32     // steps per chunk
#define NB   15     // boundary chunks stored (0..14)
#define TAPS 9
#define NPT  4      // n-rows per pass1a thread

// ---------------- Pass 1a: per-chunk LOCAL sums ----------------
// grid (8, 26, 15): x = f-slice (XCD), y = 16-row band, z = chunk.
__global__ __launch_bounds__(256) void sith_pass1a(
    const float* __restrict__ inp, const float* __restrict__ d,
    float* __restrict__ P)
{
    int fs = blockIdx.x;
    int a  = blockIdx.y;
    int b  = blockIdx.z;
    int tid = threadIdx.x;
    int lane = tid & 63;
    int y = tid >> 6;
    int n0 = a * 16 + y * NPT;
    if (n0 >= NN) return;
    int f = fs * 64 + lane;

    float dreg[NPT], st[NPT];
    #pragma unroll
    for (int q = 0; q < NPT; ++q) {
        dreg[q] = d[n0 + q];
        st[q] = 0.f;
    }
    const float* ip = inp + b * TC * NF + f;
    #pragma unroll
    for (int tt = 0; tt < TC; tt += 8) {
        float x[8];
        #pragma unroll
        for (int u = 0; u < 8; ++u) x[u] = ip[(tt + u) * NF];
        #pragma unroll
        for (int u = 0; u < 8; ++u) {
            #pragma unroll
            for (int q = 0; q < NPT; ++q)
                st[q] = fmaf(dreg[q], st[q], x[u]);
        }
    }
    #pragma unroll
    for (int q = 0; q < NPT; ++q)
        P[b * (NN * NF) + (n0 + q) * NF + f] = st[q];
}

// ---------------- Pass 1b: in-place cross-chunk scan ----------------
// grid (8, 102): x = f-slice (XCD-pinned, L2-local), y -> 4 n-rows.
// S_b = L_b + d^32 * S_{b-1}.
__global__ __launch_bounds__(256) void sith_pass1b(
    const float* __restrict__ d, float* __restrict__ P)
{
    int fs = blockIdx.x;
    int n  = blockIdx.y * 4 + (threadIdx.x >> 6);   // 0..407
    int f  = fs * 64 + (threadIdx.x & 63);
    float dn = d[n];
    float d2 = dn * dn, d4 = d2 * d2, d8 = d4 * d4, d16 = d8 * d8;
    float d32 = d16 * d16;

    float* Pb = P + n * NF + f;
    float v[NB];
    #pragma unroll
    for (int b = 0; b < NB; ++b) v[b] = Pb[b * (NN * NF)];
    float acc = v[0];
    #pragma unroll
    for (int b = 1; b < NB; ++b) {
        acc = fmaf(d32, acc, v[b]);
        Pb[b * (NN * NF)] = acc;
    }
}

// ---------------- Pass 2: scan + projection, contiguous wave stores -----
// grid (50, 16): x = o-pair, y = chunk c. 256 thr = 4 waves:
// wave w -> (oo = w>>1, fh = w&1); o = bx*2 + oo; lane owns f = fh*256+lane*4.
__global__ __launch_bounds__(256) void sith_pass2(
    const float* __restrict__ inp, const float* __restrict__ invL,
    const float* __restrict__ d, const float* __restrict__ decay,
    const float* __restrict__ subset, const float* __restrict__ P,
    float* __restrict__ out)
{
    int bx = blockIdx.x;                  // 0..49
    int c  = blockIdx.y;                  // 0..15
    int tid = threadIdx.x;
    int lane = tid & 63;
    int w = tid >> 6;                     // 0..3
    int o  = bx * 2 + (w >> 1);           // 0..99
    int f0 = (w & 1) * 256 + lane * 4;    // float4 base, 0..508
    int nb = 4 * o;                       // taps n = nb..nb+8, max 404 < 408

    float d9[TAPS], L9[TAPS];
    #pragma unroll
    for (int j = 0; j < TAPS; ++j) {
        int n = nb + j;
        d9[j] = d[n];
        L9[j] = invL[o * NN + n] * subset[o] * decay[n];
    }

    float p[TAPS][4];
    if (c == 0) {
        #pragma unroll
        for (int j = 0; j < TAPS; ++j)
            #pragma unroll
            for (int e = 0; e < 4; ++e) p[j][e] = 0.f;
    } else {
        const float* Pb = P + (c - 1) * (NN * NF) + f0;
        #pragma unroll
        for (int j = 0; j < TAPS; ++j) {
            float4 v = *reinterpret_cast<const float4*>(&Pb[(nb + j) * NF]);
            p[j][0] = v.x; p[j][1] = v.y; p[j][2] = v.z; p[j][3] = v.w;
        }
    }

    const float* ip = inp + f0;
    int t0 = c * TC;
    int obase = (t0 * NO + o) * NF + f0;

#define SITH_STEP(xv)                                                      \
    {                                                                      \
        _Pragma("unroll")                                                  \
        for (int j = 0; j < TAPS; ++j) {                                   \
            p[j][0] = fmaf(d9[j], p[j][0], (xv).x);                        \
            p[j][1] = fmaf(d9[j], p[j][1], (xv).y);                        \
            p[j][2] = fmaf(d9[j], p[j][2], (xv).z);                        \
            p[j][3] = fmaf(d9[j], p[j][3], (xv).w);                        \
        }                                                                  \
        float4 acc;                                                        \
        acc.x = acc.y = acc.z = acc.w = 0.f;                               \
        _Pragma("unroll")                                                  \
        for (int j = 0; j < TAPS; ++j) {                                   \
            acc.x = fmaf(L9[j], p[j][0], acc.x);                           \
            acc.y = fmaf(L9[j], p[j][1], acc.y);                           \
            acc.z = fmaf(L9[j], p[j][2], acc.z);                           \
            acc.w = fmaf(L9[j], p[j][3], acc.w);                           \
        }                                                                  \
        *reinterpret_cast<float4*>(&out[obase]) = acc;                     \
        obase += NO * NF;                                                  \
    }

    // rotated prefetch: next 4-group's x float4s issue before current steps.
    float4 xb0 = *reinterpret_cast<const float4*>(&ip[(t0 + 0) * NF]);
    float4 xb1 = *reinterpret_cast<const float4*>(&ip[(t0 + 1) * NF]);
    float4 xb2 = *reinterpret_cast<const float4*>(&ip[(t0 + 2) * NF]);
    float4 xb3 = *reinterpret_cast<const float4*>(&ip[(t0 + 3) * NF]);

    for (int tq = 0; tq < TC; tq += 4) {
        int tp = t0 + tq + 4;
        float4 xn0 = *reinterpret_cast<const float4*>(&ip[((tp + 0) & 511) * NF]);
        float4 xn1 = *reinterpret_cast<const float4*>(&ip[((tp + 1) & 511) * NF]);
        float4 xn2 = *reinterpret_cast<const float4*>(&ip[((tp + 2) & 511) * NF]);
        float4 xn3 = *reinterpret_cast<const float4*>(&ip[((tp + 3) & 511) * NF]);

        SITH_STEP(xb0);
        SITH_STEP(xb1);
        SITH_STEP(xb2);
        SITH_STEP(xb3);

        xb0 = xn0; xb1 = xn1; xb2 = xn2; xb3 = xn3;
    }
#undef SITH_STEP
}

extern "C" void kernel_launch(void* const* d_in, const int* in_sizes, int n_in,
                              void* d_out, int out_size, void* d_ws, size_t ws_size,
                              hipStream_t stream)
{
    const float* inp    = (const float*)d_in[0];
    const float* invL   = (const float*)d_in[1];
    const float* d      = (const float*)d_in[2];
    const float* decay  = (const float*)d_in[3];
    const float* subset = (const float*)d_in[4];
    float* out = (float*)d_out;
    float* P   = (float*)d_ws;   // 15 * 408 * 512 * 4 B = 12.5 MB

    sith_pass1a<<<dim3(8, 26, NB), 256, 0, stream>>>(inp, d, P);
    sith_pass1b<<<dim3(8, 102), 256, 0, stream>>>(d, P);
    sith_pass2<<<dim3(50, NC), 256, 0, stream>>>(inp, invL, d, decay, subset, P, out);
}

// Round 26
// 40.039 us; speedup vs baseline: 1.2738x; 1.1586x over previous
//
#include <hip/hip_runtime.h>

// SITH: out[t,o,f] = subset[o] * sum_n invL_sub[o,n] * ts[t,n,f]
//   ts[t,n,f] = d[n]*ts[t-1,n,f] + decay[n]*inp[t,f]
// invL_sub row o EXACTLY banded: n in [4o, 4o+8] (9 taps). State unscaled;
// decay*subset folded into taps.
//
// R24 = best verified pieces composed:
//  - pass1a (R13): per-chunk local sums, grid (8,26,15), fully parallel.
//  - pass1b (R19): XCD-pinned in-place d^32 Horner -> true boundary states.
//    Removes ~107 MB of per-block Horner L2 traffic and the c-graded tail
//    that R14 paid in pass2 init.
//  - pass2 (R14 loop, R11 init): uniform 25-load direct init, XCD-pinned
//    fs=bx&7, rotated prefetch, batched 20-store groups.

#define NF   512
#define NN   408
#define NO   100
#define NC   16     // time chunks
#define TC   32     // steps per chunk
#define NB   15     // boundary chunks stored (0..14)
#define TAPS 9
#define OPG  5      // outputs per o-group
#define NG   20     // o-groups (NG*OPG == NO)
#define ROWS 25     // state rows per o-group window [20g, 20g+24]
#define NPT  4      // n-rows per pass1a thread

// ---------------- Pass 1a: per-chunk LOCAL sums ----------------
// grid (8, 26, 15): x = f-slice (XCD), y = 16-row band, z = chunk.
__global__ __launch_bounds__(256) void sith_pass1a(
    const float* __restrict__ inp, const float* __restrict__ d,
    float* __restrict__ P)
{
    int fs = blockIdx.x;
    int a  = blockIdx.y;
    int b  = blockIdx.z;
    int tid = threadIdx.x;
    int lane = tid & 63;
    int y = tid >> 6;
    int n0 = a * 16 + y * NPT;
    if (n0 >= NN) return;
    int f = fs * 64 + lane;

    float dreg[NPT], st[NPT];
    #pragma unroll
    for (int q = 0; q < NPT; ++q) {
        dreg[q] = d[n0 + q];
        st[q] = 0.f;
    }
    const float* ip = inp + b * TC * NF + f;
    #pragma unroll
    for (int tt = 0; tt < TC; tt += 8) {
        float x[8];
        #pragma unroll
        for (int u = 0; u < 8; ++u) x[u] = ip[(tt + u) * NF];
        #pragma unroll
        for (int u = 0; u < 8; ++u) {
            #pragma unroll
            for (int q = 0; q < NPT; ++q)
                st[q] = fmaf(dreg[q], st[q], x[u]);
        }
    }
    #pragma unroll
    for (int q = 0; q < NPT; ++q)
        P[b * (NN * NF) + (n0 + q) * NF + f] = st[q];
}

// ---------------- Pass 1b: in-place cross-chunk scan ----------------
// grid (8, 102): x = f-slice (XCD-pinned, L2-local), y -> 4 n-rows.
// S_b = L_b + d^32 * S_{b-1}.
__global__ __launch_bounds__(256) void sith_pass1b(
    const float* __restrict__ d, float* __restrict__ P)
{
    int fs = blockIdx.x;
    int n  = blockIdx.y * 4 + (threadIdx.x >> 6);   // 0..407
    int f  = fs * 64 + (threadIdx.x & 63);
    float dn = d[n];
    float d2 = dn * dn, d4 = d2 * d2, d8 = d4 * d4, d16 = d8 * d8;
    float d32 = d16 * d16;

    float* Pb = P + n * NF + f;
    float v[NB];
    #pragma unroll
    for (int b = 0; b < NB; ++b) v[b] = Pb[b * (NN * NF)];
    float acc = v[0];
    #pragma unroll
    for (int b = 1; b < NB; ++b) {
        acc = fmaf(d32, acc, v[b]);
        Pb[b * (NN * NF)] = acc;
    }
}

// ---------------- Pass 2: uniform init + scan + projection --------------
// grid (40, 16): x = oc*8 + fs (fs = bx&7 = XCD), y = chunk c.
// 256 thr = 4 waves; lane = f (64 consecutive), wave w -> g = oc*4 + w.
__global__ __launch_bounds__(256) void sith_pass2(
    const float* __restrict__ inp, const float* __restrict__ invL,
    const float* __restrict__ d, const float* __restrict__ decay,
    const float* __restrict__ subset, const float* __restrict__ P,
    float* __restrict__ out)
{
    int bx = blockIdx.x;                  // 0..39
    int fs = bx & 7;
    int oc = bx >> 3;                     // 0..4
    int c  = blockIdx.y;                  // 0..15
    int tid = threadIdx.x;
    int lane = tid & 63;
    int w = tid >> 6;
    int g = oc * 4 + w;                   // 0..19
    int f = fs * 64 + lane;
    int nbase = NG * g;                   // row j -> n = nbase + j, j in [0,25)

    float dreg[ROWS], p[ROWS];
    #pragma unroll
    for (int j = 0; j < ROWS; ++j) {
        int n = nbase + j;                // <= 404 < 408: no guards
        dreg[j] = d[n];
        p[j] = (c == 0) ? 0.f : P[(c - 1) * (NN * NF) + n * NF + f];
    }

    float L[OPG][TAPS];
    #pragma unroll
    for (int k = 0; k < OPG; ++k) {
        int o = OPG * g + k;              // < 100 always
        float sub = subset[o];
        #pragma unroll
        for (int dd = 0; dd < TAPS; ++dd) {
            int n = nbase + 4 * k + dd;   // = 4o + dd, exact band
            L[k][dd] = invL[o * NN + n] * sub * decay[n];
        }
    }

    const float* ip = inp + f;
    int t0 = c * TC;
    int obase = (t0 * NO + OPG * g) * NF + f;

#define SITH_STEP(s, xv)                                                   \
    {                                                                      \
        _Pragma("unroll")                                                  \
        for (int j = 0; j < ROWS; ++j)                                     \
            p[j] = fmaf(dreg[j], p[j], (xv));                              \
        _Pragma("unroll")                                                  \
        for (int k = 0; k < OPG; ++k) {                                    \
            float a0 = 0.f;                                                \
            _Pragma("unroll")                                              \
            for (int dd = 0; dd < TAPS; ++dd)                              \
                a0 = fmaf(L[k][dd], p[4 * k + dd], a0);                    \
            acc[s][k] = a0;                                                \
        }                                                                  \
    }

    // rotated prefetch: next 4-group's x loads issue before current steps.
    float xb0 = ip[(t0 + 0) * NF];
    float xb1 = ip[(t0 + 1) * NF];
    float xb2 = ip[(t0 + 2) * NF];
    float xb3 = ip[(t0 + 3) * NF];

    for (int tq = 0; tq < TC; tq += 4) {
        int tp = t0 + tq + 4;
        float xn0 = ip[((tp + 0) & 511) * NF];
        float xn1 = ip[((tp + 1) & 511) * NF];
        float xn2 = ip[((tp + 2) & 511) * NF];
        float xn3 = ip[((tp + 3) & 511) * NF];

        float acc[4][OPG];
        SITH_STEP(0, xb0);
        SITH_STEP(1, xb1);
        SITH_STEP(2, xb2);
        SITH_STEP(3, xb3);

        #pragma unroll
        for (int s = 0; s < 4; ++s) {
            #pragma unroll
            for (int k = 0; k < OPG; ++k)
                __builtin_nontemporal_store(acc[s][k],
                    &out[obase + (s * NO + k) * NF]);
        }
        obase += 4 * NO * NF;

        xb0 = xn0; xb1 = xn1; xb2 = xn2; xb3 = xn3;
    }
#undef SITH_STEP
}

extern "C" void kernel_launch(void* const* d_in, const int* in_sizes, int n_in,
                              void* d_out, int out_size, void* d_ws, size_t ws_size,
                              hipStream_t stream)
{
    const float* inp    = (const float*)d_in[0];
    const float* invL   = (const float*)d_in[1];
    const float* d      = (const float*)d_in[2];
    const float* decay  = (const float*)d_in[3];
    const float* subset = (const float*)d_in[4];
    float* out = (float*)d_out;
    float* P   = (float*)d_ws;   // 15 * 408 * 512 * 4 B = 12.5 MB

    sith_pass1a<<<dim3(8, 26, NB), 256, 0, stream>>>(inp, d, P);
    sith_pass1b<<<dim3(8, 102), 256, 0, stream>>>(d, P);
    sith_pass2<<<dim3(40, NC), 256, 0, stream>>>(inp, invL, d, decay, subset, P, out);
}

// Round 27
// 37.098 us; speedup vs baseline: 1.3748x; 1.0793x over previous
//
#include <hip/hip_runtime.h>

// SITH: out[t,o,f] = subset[o] * sum_n invL_sub[o,n] * ts[t,n,f]
//   ts[t,n,f] = d[n]*ts[t-1,n,f] + decay[n]*inp[t,f]
// invL_sub row o EXACTLY banded: n in [4o, 4o+8] (9 taps). State unscaled;
// decay*subset folded into taps.
//
// R27 = R14 (best measured, 36.38 us) with ONE change: plain stores instead
// of nontemporal. Final clean A/B on the write path: nt bypasses L2
// write-allocate; plain lets L2 merge the 256-B segments into full lines.

#define NF   512
#define NN   408
#define NO   100
#define NC   16     // time chunks
#define TC   32     // steps per chunk
#define NB   15     // chunk-local sums stored (chunks 0..14)
#define TAPS 9
#define OPG  5      // outputs per o-group
#define NG   20     // o-groups (NG*OPG == NO)
#define ROWS 25     // state rows per o-group window [20g, 20g+24]
#define NPT  4      // n-rows per pass1 thread

// ---------------- Pass 1: per-chunk LOCAL sums ----------------
// grid (8, 26, 15): x = f-slice (XCD), y = 16-row band, z = chunk.
__global__ __launch_bounds__(256) void sith_pass1(
    const float* __restrict__ inp, const float* __restrict__ d,
    float* __restrict__ P)
{
    int fs = blockIdx.x;                  // 0..7  == XCD
    int a  = blockIdx.y;                  // 0..25
    int b  = blockIdx.z;                  // 0..14
    int tid = threadIdx.x;
    int lane = tid & 63;
    int y = tid >> 6;                     // 0..3
    int n0 = a * 16 + y * NPT;
    if (n0 >= NN) return;                 // a=25, y>=2
    int f = fs * 64 + lane;

    float dreg[NPT], st[NPT];
    #pragma unroll
    for (int q = 0; q < NPT; ++q) {
        dreg[q] = d[n0 + q];
        st[q] = 0.f;
    }

    const float* ip = inp + b * TC * NF + f;
    #pragma unroll
    for (int tt = 0; tt < TC; tt += 8) {
        float x[8];
        #pragma unroll
        for (int u = 0; u < 8; ++u)
            x[u] = ip[(tt + u) * NF];
        #pragma unroll
        for (int u = 0; u < 8; ++u) {
            #pragma unroll
            for (int q = 0; q < NPT; ++q)
                st[q] = fmaf(dreg[q], st[q], x[u]);
        }
    }
    #pragma unroll
    for (int q = 0; q < NPT; ++q)
        P[b * (NN * NF) + (n0 + q) * NF + f] = st[q];
}

// ---------------- Pass 2: boundary reconstruct + scan + projection --------
// grid (40, 16): x = oc*8 + fs (fs = bx&7 = XCD), y = chunk c.
// 256 thr = 4 waves; lane = f (64 consecutive), wave w -> g = oc*4 + w.
// Boundary state S_{c-1} = Horner_{k=0..c-1}(d^32, Plocal[k]).
__global__ __launch_bounds__(256) void sith_pass2(
    const float* __restrict__ inp, const float* __restrict__ invL,
    const float* __restrict__ d, const float* __restrict__ decay,
    const float* __restrict__ subset, const float* __restrict__ P,
    float* __restrict__ out)
{
    int bx = blockIdx.x;                  // 0..39
    int fs = bx & 7;
    int oc = bx >> 3;                     // 0..4
    int c  = blockIdx.y;                  // 0..15
    int tid = threadIdx.x;
    int lane = tid & 63;
    int w = tid >> 6;
    int g = oc * 4 + w;                   // 0..19
    int f = fs * 64 + lane;
    int nbase = NG * g;                   // row j -> n = nbase + j, j in [0,25)

    float dreg[ROWS], p[ROWS];
    #pragma unroll
    for (int j = 0; j < ROWS; ++j)
        dreg[j] = d[nbase + j];           // n <= 404 < 408: no guards

    // boundary reconstruction from chunk-locals (L2-pinned on this XCD)
    if (c == 0) {
        #pragma unroll
        for (int j = 0; j < ROWS; ++j) p[j] = 0.f;
    } else {
        float d32[ROWS];
        #pragma unroll
        for (int j = 0; j < ROWS; ++j) {
            float d2 = dreg[j] * dreg[j];
            float d4 = d2 * d2, d8 = d4 * d4, d16 = d8 * d8;
            d32[j] = d16 * d16;
        }
        const float* Pb = P + nbase * NF + f;
        #pragma unroll
        for (int j = 0; j < ROWS; ++j)
            p[j] = Pb[j * NF];            // Plocal[0]
        for (int k = 1; k < c; ++k) {     // runtime trip count 0..14
            const float* Pk = Pb + k * (NN * NF);
            #pragma unroll
            for (int j = 0; j < ROWS; ++j)
                p[j] = fmaf(d32[j], p[j], Pk[j * NF]);
        }
    }

    float L[OPG][TAPS];
    #pragma unroll
    for (int k = 0; k < OPG; ++k) {
        int o = OPG * g + k;              // < 100 always
        float sub = subset[o];
        #pragma unroll
        for (int dd = 0; dd < TAPS; ++dd) {
            int n = nbase + 4 * k + dd;   // = 4o + dd, exact band
            L[k][dd] = invL[o * NN + n] * sub * decay[n];
        }
    }

    const float* ip = inp + f;
    int t0 = c * TC;
    int obase = (t0 * NO + OPG * g) * NF + f;

    // one step: recurrence + accumulate projections into acc[s][*]
#define SITH_STEP(s, xv)                                                   \
    {                                                                      \
        _Pragma("unroll")                                                  \
        for (int j = 0; j < ROWS; ++j)                                     \
            p[j] = fmaf(dreg[j], p[j], (xv));                              \
        _Pragma("unroll")                                                  \
        for (int k = 0; k < OPG; ++k) {                                    \
            float a0 = 0.f;                                                \
            _Pragma("unroll")                                              \
            for (int dd = 0; dd < TAPS; ++dd)                              \
                a0 = fmaf(L[k][dd], p[4 * k + dd], a0);                    \
            acc[s][k] = a0;                                                \
        }                                                                  \
    }

    // rotated prefetch: next 4-group's x loads issue before current steps.
    float xb0 = ip[(t0 + 0) * NF];
    float xb1 = ip[(t0 + 1) * NF];
    float xb2 = ip[(t0 + 2) * NF];
    float xb3 = ip[(t0 + 3) * NF];

    for (int tq = 0; tq < TC; tq += 4) {
        int tp = t0 + tq + 4;
        float xn0 = ip[((tp + 0) & 511) * NF];
        float xn1 = ip[((tp + 1) & 511) * NF];
        float xn2 = ip[((tp + 2) & 511) * NF];
        float xn3 = ip[((tp + 3) & 511) * NF];

        float acc[4][OPG];
        SITH_STEP(0, xb0);
        SITH_STEP(1, xb1);
        SITH_STEP(2, xb2);
        SITH_STEP(3, xb3);

        // burst: 20 back-to-back PLAIN stores (L2 write-back path)
        #pragma unroll
        for (int s = 0; s < 4; ++s) {
            #pragma unroll
            for (int k = 0; k < OPG; ++k)
                out[obase + (s * NO + k) * NF] = acc[s][k];
        }
        obase += 4 * NO * NF;

        xb0 = xn0; xb1 = xn1; xb2 = xn2; xb3 = xn3;
    }
#undef SITH_STEP
}

extern "C" void kernel_launch(void* const* d_in, const int* in_sizes, int n_in,
                              void* d_out, int out_size, void* d_ws, size_t ws_size,
                              hipStream_t stream)
{
    const float* inp    = (const float*)d_in[0];
    const float* invL   = (const float*)d_in[1];
    const float* d      = (const float*)d_in[2];
    const float* decay  = (const float*)d_in[3];
    const float* subset = (const float*)d_in[4];
    float* out = (float*)d_out;
    float* P   = (float*)d_ws;   // 15 * 408 * 512 * 4 B = 12.5 MB chunk-local sums

    sith_pass1<<<dim3(8, 26, NB), 256, 0, stream>>>(inp, d, P);
    sith_pass2<<<dim3(40, NC), 256, 0, stream>>>(inp, invL, d, decay, subset, P, out);
}